// Round 11
// baseline (14.417 us; speedup 1.0000x reference)
//
#include <hip/hip_runtime.h>
#include <hip/hip_bf16.h>

#define D_    64
#define BH    32
#define LCH   64            // chunk length
#define NC    16            // chunks per (b,h)
#define DECAY 0.95f
#define LN_D  0.051293294f  // -ln(0.95)
#define DEC64 0.03752432f   // 0.95^64
#define LDSB  68            // padded bf16 LDS row

typedef __attribute__((ext_vector_type(8))) short          bf8_t;  // MFMA A/B frag
typedef __attribute__((ext_vector_type(8))) unsigned short u16x8;
typedef __attribute__((ext_vector_type(4))) float          f32x4;
typedef unsigned short u16;

static __device__ __forceinline__ u16 f2bf(float f) {
    return __builtin_bit_cast(u16, __float2bfloat16(f));   // HW v_cvt path
}
static __device__ __forceinline__ bf8_t frag_rr(float4 a, float4 b, float sc) {
    u16x8 r;
    r[0] = f2bf(a.x * sc); r[1] = f2bf(a.y * sc); r[2] = f2bf(a.z * sc); r[3] = f2bf(a.w * sc);
    r[4] = f2bf(b.x * sc); r[5] = f2bf(b.y * sc); r[6] = f2bf(b.z * sc); r[7] = f2bf(b.w * sc);
    return __builtin_bit_cast(bf8_t, r);
}
static __device__ __forceinline__ bf8_t frag_g(const float* g) {
    u16x8 r;
    #pragma unroll
    for (int z = 0; z < 8; ++z) r[z] = f2bf(g[z]);
    return __builtin_bit_cast(bf8_t, r);
}

// ---------------------------------------------------------------------------
// Fused chunked linear attention, 8-wave blocks (512 thr) for 2x TLP:
//   wave (wm,wn): i/e-slab = 16 rows [16*wm, 16*wm+16), N-column half wn.
//   S_init(c) ~= L(c-1) + dec64*L(c-2); O = decay^{i+1} q@S + tril(..)@V.
// 2 barriers; K'/ST/VT column-XOR-swizzled; 4096 total waves = 4/SIMD.
// ---------------------------------------------------------------------------
__global__ __launch_bounds__(512, 4) void kv_fused(const float* __restrict__ q,
                                                   const float* __restrict__ k,
                                                   const float* __restrict__ v,
                                                   float* __restrict__ o) {
    __shared__ u16 KT[2][D_][LDSB];   // swizzled prev K' [d][j]
    __shared__ u16 VT[D_][LDSB];      // swizzled own-chunk V^T [e][j]
    __shared__ u16 ST[D_][LDSB];      // swizzled S^T [e][d]
    __shared__ u16 As[LCH][LDSB];     // masked decayed A [i][j]

    // XCD-aware bijective swizzle (512 blocks % 8 == 0)
    const int bid = (int)blockIdx.x;
    const int lb  = (bid & 7) * ((BH * NC) / 8) + (bid >> 3);
    const int bh  = lb >> 4;
    const int c   = lb & (NC - 1);

    const int tid  = threadIdx.x;
    const size_t bhb  = (size_t)bh * (NC * LCH) * D_;
    const size_t base = bhb + (size_t)c * LCH * D_;

    const int lane = tid & 63;
    const int w8   = tid >> 6;               // wave 0..7
    const int wm   = w8 >> 1;                // row slab
    const int wn   = w8 & 1;                 // column half
    const int fr   = lane & 15, hi = lane >> 4;
    const int fk   = hi << 3;
    const int i0   = wm << 4;
    const int ib   = i0 + (hi << 2);

    const int sj   = tid >> 3;               // staging: time row 0..63
    const int sc8  = (tid & 7) << 3;         // staging: 8-row group of d/e
    const int sjx  = sj ^ (((sc8 >> 4) & 3) << 4);  // swizzled col

    // ================= one load round =================
    float pv1[2][8], pv0[2][8];
    if (c >= 1) {
        const float* vs = v + base - (size_t)LCH * D_ + i0 + fr;
        #pragma unroll
        for (int kt = 0; kt < 2; ++kt)
            #pragma unroll
            for (int z = 0; z < 8; ++z)
                pv1[kt][z] = vs[(size_t)(kt * 32 + fk + z) * D_];
    }
    if (c >= 2) {
        const float* vs = v + base - (size_t)(2 * LCH) * D_ + i0 + fr;
        #pragma unroll
        for (int kt = 0; kt < 2; ++kt)
            #pragma unroll
            for (int z = 0; z < 8; ++z)
                pv0[kt][z] = vs[(size_t)(kt * 32 + fk + z) * D_];
    }
    const float* qrow = q + base + (size_t)(i0 + fr) * D_;
    const float4 qa0 = *(const float4*)(qrow + fk);
    const float4 qa1 = *(const float4*)(qrow + fk + 4);
    const float4 qb0 = *(const float4*)(qrow + 32 + fk);
    const float4 qb1 = *(const float4*)(qrow + 32 + fk + 4);

    float4 k1[2], k0[2];
    if (c >= 1) {
        const float* kg = k + base - (size_t)LCH * D_ + sj * D_ + sc8;
        k1[0] = *(const float4*)kg;  k1[1] = *(const float4*)(kg + 4);
    }
    if (c >= 2) {
        const float* kg = k + base - (size_t)(2 * LCH) * D_ + sj * D_ + sc8;
        k0[0] = *(const float4*)kg;  k0[1] = *(const float4*)(kg + 4);
    }
    float4 vo[2];
    {
        const float* vg = v + base + sj * D_ + sc8;
        vo[0] = *(const float4*)vg;  vo[1] = *(const float4*)(vg + 4);
    }

    // ---- early conversions
    const bf8_t aq0 = frag_rr(qa0, qa1, 1.f);
    const bf8_t aq1 = frag_rr(qb0, qb1, 1.f);
    bf8_t av1[2], av0[2];
    if (c >= 1) { av1[0] = frag_g(pv1[0]); av1[1] = frag_g(pv1[1]); }
    if (c >= 2) { av0[0] = frag_g(pv0[0]); av0[1] = frag_g(pv0[1]); }

    // ---- transpose-stage K' (swizzled)
    const float wdec = __expf(-LN_D * (float)(63 - sj));    // decay^{63-sj}
    if (c >= 1) {
        #pragma unroll
        for (int m = 0; m < 2; ++m) {
            const int cb = sc8 + 4 * m;
            KT[1][cb + 0][sjx] = f2bf(k1[m].x * wdec);
            KT[1][cb + 1][sjx] = f2bf(k1[m].y * wdec);
            KT[1][cb + 2][sjx] = f2bf(k1[m].z * wdec);
            KT[1][cb + 3][sjx] = f2bf(k1[m].w * wdec);
        }
    }
    if (c >= 2) {
        const float wd0 = wdec * DEC64;
        #pragma unroll
        for (int m = 0; m < 2; ++m) {
            const int cb = sc8 + 4 * m;
            KT[0][cb + 0][sjx] = f2bf(k0[m].x * wd0);
            KT[0][cb + 1][sjx] = f2bf(k0[m].y * wd0);
            KT[0][cb + 2][sjx] = f2bf(k0[m].z * wd0);
            KT[0][cb + 3][sjx] = f2bf(k0[m].w * wd0);
        }
    }
    __syncthreads();                                        // barrier 1

    // ---- issue phase-2 K loads (own jt half; latency under phase-1 MFMA)
    float4 kp[2][4];
    #pragma unroll
    for (int jt2 = 0; jt2 < 2; ++jt2) {
        const int jt = 2 * wn + jt2;
        if (jt <= wm) {
            const float* krow = k + base + (size_t)(jt * 16 + fr) * D_;
            kp[jt2][0] = *(const float4*)(krow + fk);
            kp[jt2][1] = *(const float4*)(krow + fk + 4);
            kp[jt2][2] = *(const float4*)(krow + 32 + fk);
            kp[jt2][3] = *(const float4*)(krow + 32 + fk + 4);
        }
    }

    // ---- phase-1 MFMA: S^T[e][d], own dt half (2 tiles)
    f32x4 accS[2];
    accS[0] = (f32x4){0.f, 0.f, 0.f, 0.f};
    accS[1] = (f32x4){0.f, 0.f, 0.f, 0.f};
    __builtin_amdgcn_s_setprio(1);
    if (c >= 1) {
        #pragma unroll
        for (int kt = 0; kt < 2; ++kt)
            #pragma unroll
            for (int dt2 = 0; dt2 < 2; ++dt2) {
                const int dt = 2 * wn + dt2;
                bf8_t bk = *(const bf8_t*)&KT[1][dt * 16 + fr][(kt * 32 + fk) ^ (dt << 4)];
                accS[dt2] = __builtin_amdgcn_mfma_f32_16x16x32_bf16(av1[kt], bk, accS[dt2], 0, 0, 0);
            }
    }
    if (c >= 2) {
        #pragma unroll
        for (int kt = 0; kt < 2; ++kt)
            #pragma unroll
            for (int dt2 = 0; dt2 < 2; ++dt2) {
                const int dt = 2 * wn + dt2;
                bf8_t bk = *(const bf8_t*)&KT[0][dt * 16 + fr][(kt * 32 + fk) ^ (dt << 4)];
                accS[dt2] = __builtin_amdgcn_mfma_f32_16x16x32_bf16(av0[kt], bk, accS[dt2], 0, 0, 0);
            }
    }
    __builtin_amdgcn_s_setprio(0);

    // ---- write S^T -> ST (swizzled), own dt half
    if (c > 0) {
        #pragma unroll
        for (int dt2 = 0; dt2 < 2; ++dt2)
            #pragma unroll
            for (int r = 0; r < 4; ++r)
                ST[ib + r][(((2 * wn + dt2) ^ wm) << 4) + fr] = f2bf(accS[dt2][r]);
    }
    // ---- stage own-chunk V^T (swizzled)
    #pragma unroll
    for (int m = 0; m < 2; ++m) {
        const int cb = sc8 + 4 * m;
        VT[cb + 0][sjx] = f2bf(vo[m].x);
        VT[cb + 1][sjx] = f2bf(vo[m].y);
        VT[cb + 2][sjx] = f2bf(vo[m].z);
        VT[cb + 3][sjx] = f2bf(vo[m].w);
    }

    // ---- QK^T, own jt half
    f32x4 accA[2];
    accA[0] = (f32x4){0.f, 0.f, 0.f, 0.f};
    accA[1] = (f32x4){0.f, 0.f, 0.f, 0.f};
    __builtin_amdgcn_s_setprio(1);
    #pragma unroll
    for (int jt2 = 0; jt2 < 2; ++jt2) {
        const int jt = 2 * wn + jt2;
        if (jt <= wm) {
            const float ksc = __expf(LN_D * (float)(jt * 16 + fr));   // decay^-j
            bf8_t b0 = frag_rr(kp[jt2][0], kp[jt2][1], ksc);
            bf8_t b1 = frag_rr(kp[jt2][2], kp[jt2][3], ksc);
            accA[jt2] = __builtin_amdgcn_mfma_f32_16x16x32_bf16(aq0, b0, accA[jt2], 0, 0, 0);
            accA[jt2] = __builtin_amdgcn_mfma_f32_16x16x32_bf16(aq1, b1, accA[jt2], 0, 0, 0);
        }
    }
    __builtin_amdgcn_s_setprio(0);

    // per-row decay^i scales
    const float db = __expf(-LN_D * (float)ib);
    float isc[4];
    isc[0] = db; isc[1] = db * DECAY; isc[2] = isc[1] * DECAY; isc[3] = isc[2] * DECAY;

    // ---- mask + scale + store A; write zeros up to jt<=wm+1 so every column
    // O2 reads (j < 32*nk2, nk2=(wm+2)>>1) is initialized.
    #pragma unroll
    for (int jt2 = 0; jt2 < 2; ++jt2) {
        const int jt = 2 * wn + jt2;
        if (jt <= wm + 1) {
            #pragma unroll
            for (int r = 0; r < 4; ++r) {
                const int i  = ib + r;
                const int jj = jt * 16 + fr;
                float val = (jt <= wm && jj <= i) ? accA[jt2][r] * isc[r] : 0.f;
                As[i][jj] = f2bf(val);
            }
        }
    }
    __syncthreads();                                        // barrier 2

    // ---- O1 = q @ S_init (swizzled ST reads), own et half
    f32x4 accO[2];
    accO[0] = (f32x4){0.f, 0.f, 0.f, 0.f};
    accO[1] = (f32x4){0.f, 0.f, 0.f, 0.f};
    __builtin_amdgcn_s_setprio(1);
    if (c > 0) {
        #pragma unroll
        for (int et2 = 0; et2 < 2; ++et2) {
            const int et = 2 * wn + et2;
            bf8_t b0 = *(const bf8_t*)&ST[et * 16 + fr][(fk) ^ (et << 4)];
            bf8_t b1 = *(const bf8_t*)&ST[et * 16 + fr][(32 + fk) ^ (et << 4)];
            accO[et2] = __builtin_amdgcn_mfma_f32_16x16x32_bf16(aq0, b0, accO[et2], 0, 0, 0);
            accO[et2] = __builtin_amdgcn_mfma_f32_16x16x32_bf16(aq1, b1, accO[et2], 0, 0, 0);
        }
    }
    __builtin_amdgcn_s_setprio(0);
    #pragma unroll
    for (int et2 = 0; et2 < 2; ++et2)
        #pragma unroll
        for (int r = 0; r < 4; ++r)
            accO[et2][r] *= isc[r] * DECAY;                 // decay^{i+1}

    // ---- O2 += A @ V (causal K-slices; own et half)
    const int nk2 = (wm + 2) >> 1;
    __builtin_amdgcn_s_setprio(1);
    #pragma unroll
    for (int kt2 = 0; kt2 < 2; ++kt2) {
        if (kt2 < nk2) {
            bf8_t aa = *(const bf8_t*)&As[i0 + fr][kt2 * 32 + fk];
            #pragma unroll
            for (int et2 = 0; et2 < 2; ++et2) {
                const int et = 2 * wn + et2;
                bf8_t bv = *(const bf8_t*)&VT[et * 16 + fr][(kt2 * 32 + fk) ^ (et << 4)];
                accO[et2] = __builtin_amdgcn_mfma_f32_16x16x32_bf16(aa, bv, accO[et2], 0, 0, 0);
            }
        }
    }
    __builtin_amdgcn_s_setprio(0);

    // ---- store O (own et half)
    float* og = o + base;
    #pragma unroll
    for (int et2 = 0; et2 < 2; ++et2)
        #pragma unroll
        for (int r = 0; r < 4; ++r)
            og[(size_t)(ib + r) * D_ + (2 * wn + et2) * 16 + fr] = accO[et2][r];
}

// ---------------------------------------------------------------------------
extern "C" void kernel_launch(void* const* d_in, const int* in_sizes, int n_in,
                              void* d_out, int out_size, void* d_ws, size_t ws_size,
                              hipStream_t stream) {
    const float* q = (const float*)d_in[0];
    const float* k = (const float*)d_in[1];
    const float* v = (const float*)d_in[2];
    kv_fused<<<BH * NC, 512, 0, stream>>>(q, k, v, (float*)d_out);
}